// Round 4
// baseline (525.231 us; speedup 1.0000x reference)
//
#include <hip/hip_runtime.h>
#include <stdint.h>

#define DIM  1024
#define NSRC 4096
#define NTGT 4096

typedef __bf16 bf16_t;
typedef bf16_t bf16x8 __attribute__((ext_vector_type(8)));
typedef float  fx4    __attribute__((ext_vector_type(4)));

static __device__ __forceinline__ unsigned short f2bf(float f) {
  union { float f; uint32_t u; } v; v.f = f;
  return (unsigned short)((v.u + 0x7FFFu + ((v.u >> 16) & 1u)) >> 16);
}
static __device__ __forceinline__ float bf2f(unsigned short h) {
  union { uint32_t u; float f; } v; v.u = ((uint32_t)h) << 16;
  return v.f;
}

// async global->LDS, 16B per lane; lds dest is wave-uniform base + lane*16
static __device__ __forceinline__ void gl_lds16(const unsigned short* g, unsigned short* l) {
  __builtin_amdgcn_global_load_lds(
      (__attribute__((address_space(1))) const void*)g,
      (__attribute__((address_space(3))) void*)l, 16, 0, 0);
}

// ---------------- fused fp32->bf16 conversion of all four inputs ----------------
__global__ void k_convert_all(const float* __restrict__ s, const float* __restrict__ t,
                              const float* __restrict__ w0, const float* __restrict__ w1,
                              unsigned short* __restrict__ sb, unsigned short* __restrict__ tb,
                              unsigned short* __restrict__ wb0, unsigned short* __restrict__ wb1) {
  int b = blockIdx.x;
  const float* in; unsigned short* out; int idx;
  if (b < 4096)      { in = s;  out = sb;  idx = b * 256 + threadIdx.x; }
  else if (b < 8192) { in = t;  out = tb;  idx = (b - 4096) * 256 + threadIdx.x; }
  else if (b < 9216) { in = w0; out = wb0; idx = (b - 8192) * 256 + threadIdx.x; }
  else               { in = w1; out = wb1; idx = (b - 9216) * 256 + threadIdx.x; }
  float4 v = ((const float4*)in)[idx];
  ushort4 o;
  o.x = f2bf(v.x); o.y = f2bf(v.y); o.z = f2bf(v.z); o.w = f2bf(v.w);
  ((ushort4*)out)[idx] = o;
}

// transpose fp32 [R][C] -> bf16 [C][R]
__global__ void k_transpose_bf16(const float* __restrict__ in, unsigned short* __restrict__ out,
                                 int R, int C) {
  __shared__ unsigned short tile[32][33];
  int c0 = blockIdx.x * 32, r0 = blockIdx.y * 32;
  int tx = threadIdx.x, ty = threadIdx.y; // 32 x 8
  for (int i = ty; i < 32; i += 8)
    tile[i][tx] = f2bf(in[(size_t)(r0 + i) * C + c0 + tx]);
  __syncthreads();
  for (int i = ty; i < 32; i += 8)
    out[(size_t)(c0 + i) * R + r0 + tx] = tile[tx][i];
}

// ---------------- merge split-K partials (*1/rs) + K write, fused ----------------
// blocks [0,4096): aligned = sum(P[0..3]) / rs  ; [4096,12288): Kf = bf2f(Eb)/rs
__global__ void k_finalize(const float* __restrict__ P, float* __restrict__ aligned,
                           const unsigned short* __restrict__ Eb, float* __restrict__ Kf,
                           const float* __restrict__ rs) {
  int b = blockIdx.x;
  if (b < 4096) {
    int i = b * 256 + threadIdx.x;  // float4 index, row = i >> 8
    float r = 1.0f / rs[i >> 8];
    const size_t stride = (size_t)NSRC * DIM / 4;
    float4 a = ((const float4*)P)[i];
    float4 c = ((const float4*)P)[i + stride];
    float4 d = ((const float4*)P)[i + 2 * stride];
    float4 e = ((const float4*)P)[i + 3 * stride];
    float4 o = { (a.x + c.x + d.x + e.x) * r, (a.y + c.y + d.y + e.y) * r,
                 (a.z + c.z + d.z + e.z) * r, (a.w + c.w + d.w + e.w) * r };
    ((float4*)aligned)[i] = o;
  } else {
    int i = (b - 4096) * 256 + threadIdx.x; // ushort8 index, row = i >> 9
    float r = 1.0f / rs[i >> 9];
    ushort4 a = ((const ushort4*)Eb)[2 * i];
    ushort4 c = ((const ushort4*)Eb)[2 * i + 1];
    float4 o0 = { bf2f(a.x) * r, bf2f(a.y) * r, bf2f(a.z) * r, bf2f(a.w) * r };
    float4 o1 = { bf2f(c.x) * r, bf2f(c.y) * r, bf2f(c.z) * r, bf2f(c.w) * r };
    ((float4*)Kf)[2 * i]     = o0;
    ((float4*)Kf)[2 * i + 1] = o1;
  }
}

// ---------------- m97-style NT bf16 GEMM, 128x128 tile, BK=32, 256 threads ----------------
// EPI 0: dual proj (z selects set), +bias, bf16 out via LDS repack; row-sumsq atomics
// EPI 1: score: E=exp(-sqrt(max(sqs+sqt-2c,0))/T) bf16 out via LDS repack; row-sum atomics
// EPI 3: split-K (z = k-chunk), fp32 partial store via 2-pass LDS repack
template <int EPI>
__global__ void __launch_bounds__(256)
k_gemm(const unsigned short* __restrict__ A0, const unsigned short* __restrict__ B0,
       const unsigned short* __restrict__ A1, const unsigned short* __restrict__ B1,
       int N, int K,
       const float* __restrict__ bias0, const float* __restrict__ bias1,
       unsigned short* __restrict__ Cb0, unsigned short* __restrict__ Cb1,
       float* __restrict__ Cf,
       const float* __restrict__ sqs, const float* __restrict__ sqt,
       const float* __restrict__ tempPtr,
       float* __restrict__ red0, float* __restrict__ red1,
       int KS) {
  __shared__ union {
    struct { unsigned short a[128 * 32]; unsigned short b[128 * 32]; } st;
    unsigned short c16[128 * 140]; // bf16 C-tile, padded stride 140
    float          c32[64 * 130];  // fp32 half-C-tile, padded stride 130
  } sm;
  __shared__ float rsum[128];

  const unsigned short* A = A0;
  const unsigned short* B = B0;
  const float* bias = bias0;
  unsigned short* Cb = Cb0;
  float* red = red0;
  int k0 = 0, k1 = K;
  if constexpr (EPI == 0) {
    if (blockIdx.z) { A = A1; B = B1; bias = bias1; Cb = Cb1; red = red1; }
  }
  if constexpr (EPI == 3) { k0 = blockIdx.z * KS; k1 = k0 + KS; }

  const int m0 = blockIdx.y * 128;
  const int n0 = blockIdx.x * 128;
  const int tid  = threadIdx.x;
  const int lane = tid & 63;
  const int wv   = tid >> 6;
  const int wm   = wv >> 1, wn = wv & 1;

  const int c0    = wv * 2;
  const int srow  = lane >> 2;
  const int skoff = (lane & 3) * 8;
  const unsigned short* ag[2]; const unsigned short* bg[2];
  unsigned short* la[2]; unsigned short* lb[2];
#pragma unroll
  for (int j = 0; j < 2; ++j) {
    int c = c0 + j;
    ag[j] = A + (size_t)(m0 + c * 16 + srow) * K + skoff;
    bg[j] = B + (size_t)(n0 + c * 16 + srow) * K + skoff;
    la[j] = sm.st.a + c * 512;
    lb[j] = sm.st.b + c * 512;
  }

  const fx4 fzero = {0.f, 0.f, 0.f, 0.f};
  fx4 acc[4][4];
#pragma unroll
  for (int i = 0; i < 4; ++i)
#pragma unroll
    for (int j = 0; j < 4; ++j) acc[i][j] = fzero;

  const int frow = lane & 15;
  const int kq   = lane >> 4;
  const int aoff = (wm * 64 + frow) * 32 + kq * 8;
  const int boff = (wn * 64 + frow) * 32 + kq * 8;

  for (int ko = k0; ko < k1; ko += 32) {
    gl_lds16(ag[0] + ko, la[0]);
    gl_lds16(ag[1] + ko, la[1]);
    gl_lds16(bg[0] + ko, lb[0]);
    gl_lds16(bg[1] + ko, lb[1]);
    __syncthreads();
    bf16x8 af[4], bfr[4];
#pragma unroll
    for (int t = 0; t < 4; ++t) af[t]  = *(const bf16x8*)(sm.st.a + aoff + t * 512);
#pragma unroll
    for (int t = 0; t < 4; ++t) bfr[t] = *(const bf16x8*)(sm.st.b + boff + t * 512);
#pragma unroll
    for (int i = 0; i < 4; ++i)
#pragma unroll
      for (int j = 0; j < 4; ++j)
        acc[i][j] = __builtin_amdgcn_mfma_f32_16x16x32_bf16(af[i], bfr[j], acc[i][j], 0, 0, 0);
    __syncthreads();
  }

  // C/D layout: col = lane&15, row = (lane>>4)*4 + r
  const int gcol0 = n0 + wn * 64 + frow;  // + j*16
  const int lcol0 = wn * 64 + frow;

  if constexpr (EPI == 0 || EPI == 1) {
    if (tid < 128) rsum[tid] = 0.f;
    __syncthreads();
    float invT = 0.f;
    if constexpr (EPI == 1) invT = 1.0f / tempPtr[0];
#pragma unroll
    for (int i = 0; i < 4; ++i)
#pragma unroll
      for (int r = 0; r < 4; ++r) {
        const int lrow = wm * 64 + kq * 4 + i * 16 + r;
        float racc = 0.f;
        float si = 0.f;
        if constexpr (EPI == 1) si = sqs[m0 + lrow];
#pragma unroll
        for (int j = 0; j < 4; ++j) {
          float e;
          if constexpr (EPI == 0) {
            e = acc[i][j][r] + bias[gcol0 + j * 16];
          } else {
            float d2 = si + sqt[gcol0 + j * 16] - 2.0f * acc[i][j][r];
            float c = sqrtf(fmaxf(d2, 0.0f));
            e = __expf(-c * invT);
          }
          unsigned short eb = f2bf(e);
          sm.c16[lrow * 140 + lcol0 + j * 16] = eb;
          float ev = bf2f(eb);
          racc += (EPI == 0) ? ev * ev : ev; // EPI0: sumsq of ROUNDED value (consistency with bf16 dot)
        }
        racc += __shfl_xor(racc, 1, 64);
        racc += __shfl_xor(racc, 2, 64);
        racc += __shfl_xor(racc, 4, 64);
        racc += __shfl_xor(racc, 8, 64);
        if (frow == 0) atomicAdd(&rsum[lrow], racc);
      }
    __syncthreads();
    // coalesced store: 128 rows x 128 bf16
    {
      const int row = tid >> 1, ch = tid & 1;
      const unsigned short* lp = sm.c16 + row * 140 + ch * 64;
      unsigned short* gp = Cb + (size_t)(m0 + row) * N + n0 + ch * 64;
#pragma unroll
      for (int q = 0; q < 8; ++q) {
        uint2 x = *(const uint2*)(lp + q * 8);
        uint2 y = *(const uint2*)(lp + q * 8 + 4);
        uint4 v = make_uint4(x.x, x.y, y.x, y.y);
        *(uint4*)(gp + q * 8) = v;
      }
    }
    if (tid < 128) atomicAdd(&red[m0 + tid], rsum[tid]);
  } else { // EPI == 3: fp32 partials via 2-pass LDS repack
    float* Pz = Cf + (size_t)blockIdx.z * NSRC * DIM;
#pragma unroll
    for (int half = 0; half < 2; ++half) {
      __syncthreads();
      if (wm == half) {
#pragma unroll
        for (int i = 0; i < 4; ++i)
#pragma unroll
          for (int j = 0; j < 4; ++j)
#pragma unroll
            for (int r = 0; r < 4; ++r)
              sm.c32[(kq * 4 + i * 16 + r) * 130 + lcol0 + j * 16] = acc[i][j][r];
      }
      __syncthreads();
      const int row = tid >> 2, cq = tid & 3;
      const float* lp = sm.c32 + row * 130 + cq * 32;
      float* gp = Pz + (size_t)(m0 + half * 64 + row) * N + n0 + cq * 32;
#pragma unroll
      for (int q = 0; q < 8; ++q) {
        float2 a = *(const float2*)(lp + q * 4);
        float2 b = *(const float2*)(lp + q * 4 + 2);
        float4 v = make_float4(a.x, a.y, b.x, b.y);
        *(float4*)(gp + q * 4) = v;
      }
    }
  }
}

// ---------------- launch ----------------
extern "C" void kernel_launch(void* const* d_in, const int* in_sizes, int n_in,
                              void* d_out, int out_size, void* d_ws, size_t ws_size,
                              hipStream_t stream) {
  const float* source = (const float*)d_in[0];
  const float* target = (const float*)d_in[1];
  const float* W_src  = (const float*)d_in[2];
  const float* b_src  = (const float*)d_in[3];
  const float* W_tgt  = (const float*)d_in[4];
  const float* b_tgt  = (const float*)d_in[5];
  const float* temp   = (const float*)d_in[6];

  float* out     = (float*)d_out;
  float* aligned = out;                         // [NSRC][DIM]
  float* Kout    = out + (size_t)NSRC * DIM;    // final K; staging for split-K partials
  float* parts   = Kout;                        // 4 x [NSRC][DIM] fp32 = exactly 64 MB

  char* ws = (char*)d_ws;
  unsigned short* src_b  = (unsigned short*)(ws + 0);
  unsigned short* tgt_b  = (unsigned short*)(ws + 8388608);
  unsigned short* Wsrc_b = (unsigned short*)(ws + 16777216);
  unsigned short* Wtgt_b = (unsigned short*)(ws + 18874368);
  unsigned short* sp_b   = (unsigned short*)(ws + 20971520);
  unsigned short* tp_b   = (unsigned short*)(ws + 29360128);
  unsigned short* tgtT_b = (unsigned short*)(ws + 37748736);
  unsigned short* E_b    = (unsigned short*)(ws + 46137344); // 32 MB
  float* sq_s  = (float*)(ws + 79691776);                    // 16 KB
  float* sq_t  = (float*)(ws + 79708160);                    // 16 KB
  float* rsums = (float*)(ws + 79724544);                    // 16 KB

  // 0) zero sq_s, sq_t, rsums (contiguous 48 KB)
  hipMemsetAsync(sq_s, 0, 3 * NSRC * sizeof(float), stream);

  // 1) conversions + target transpose
  k_convert_all<<<10240, 256, 0, stream>>>(source, target, W_src, W_tgt,
                                           src_b, tgt_b, Wsrc_b, Wtgt_b);
  k_transpose_bf16<<<dim3(DIM / 32, NTGT / 32), dim3(32, 8), 0, stream>>>(target, tgtT_b, NTGT, DIM);

  // 2) both projections in one dispatch; epilogue also accumulates row sumsq
  k_gemm<0><<<dim3(DIM / 128, NSRC / 128, 2), 256, 0, stream>>>(
      src_b, Wsrc_b, tgt_b, Wtgt_b, DIM, DIM, b_src, b_tgt, sp_b, tp_b,
      nullptr, nullptr, nullptr, nullptr, sq_s, sq_t, 0);

  // 3) score: E bf16 -> ws, row sums -> rsums
  k_gemm<1><<<dim3(NTGT / 128, NSRC / 128, 1), 256, 0, stream>>>(
      sp_b, tp_b, nullptr, nullptr, NTGT, DIM, nullptr, nullptr, E_b, nullptr,
      nullptr, sq_s, sq_t, temp, rsums, nullptr, 0);

  // 4) E @ target: split-K x4, coalesced partial stores into d_out K region
  k_gemm<3><<<dim3(DIM / 128, NSRC / 128, 4), 256, 0, stream>>>(
      E_b, tgtT_b, nullptr, nullptr, DIM, NTGT, nullptr, nullptr, nullptr, nullptr,
      parts, nullptr, nullptr, nullptr, nullptr, nullptr, NTGT / 4);

  // 5) merge partials /rs -> aligned ; K = bf2f(E_b)/rs -> d_out K region
  k_finalize<<<12288, 256, 0, stream>>>(parts, aligned, E_b, Kout, rsums);
}

// Round 5
// 314.010 us; speedup vs baseline: 1.6727x; 1.6727x over previous
//
#include <hip/hip_runtime.h>
#include <stdint.h>

#define DIM  1024
#define NSRC 4096
#define NTGT 4096

typedef __bf16 bf16_t;
typedef bf16_t bf16x8 __attribute__((ext_vector_type(8)));
typedef float  fx4    __attribute__((ext_vector_type(4)));

static __device__ __forceinline__ unsigned short f2bf(float f) {
  union { float f; uint32_t u; } v; v.f = f;
  return (unsigned short)((v.u + 0x7FFFu + ((v.u >> 16) & 1u)) >> 16);
}
static __device__ __forceinline__ float bf2f(unsigned short h) {
  union { uint32_t u; float f; } v; v.u = ((uint32_t)h) << 16;
  return v.f;
}

// async global->LDS, 16B per lane; lds dest is wave-uniform base + lane*16
static __device__ __forceinline__ void gl_lds16(const unsigned short* g, unsigned short* l) {
  __builtin_amdgcn_global_load_lds(
      (__attribute__((address_space(1))) const void*)g,
      (__attribute__((address_space(3))) void*)l, 16, 0, 0);
}

// Permutation within each 64-element block: stored s holds true (s>>2)+16*(s&3).
// Inverse (true c comes from stored): p(c) = (c&15)*4 + (c>>4).

// ---------------- fused fp32->bf16 conversion of all four inputs ----------------
__global__ void k_convert_all(const float* __restrict__ s, const float* __restrict__ t,
                              const float* __restrict__ w0, const float* __restrict__ w1,
                              unsigned short* __restrict__ sb, unsigned short* __restrict__ tb,
                              unsigned short* __restrict__ wb0, unsigned short* __restrict__ wb1) {
  int b = blockIdx.x;
  const float* in; unsigned short* out; int idx;
  if (b < 4096)      { in = s;  out = sb;  idx = b * 256 + threadIdx.x; }
  else if (b < 8192) { in = t;  out = tb;  idx = (b - 4096) * 256 + threadIdx.x; }
  else if (b < 9216) { in = w0; out = wb0; idx = (b - 8192) * 256 + threadIdx.x; }
  else               { in = w1; out = wb1; idx = (b - 9216) * 256 + threadIdx.x; }
  float4 v = ((const float4*)in)[idx];
  ushort4 o;
  o.x = f2bf(v.x); o.y = f2bf(v.y); o.z = f2bf(v.z); o.w = f2bf(v.w);
  ((ushort4*)out)[idx] = o;
}

// transpose fp32 target [R=NTGT][C=DIM] -> bf16 tgtT_b[n][s] = target[true(s)][n]
// (contraction dim stored in the same permuted order E_b uses)
__global__ void k_transpose_bf16(const float* __restrict__ in, unsigned short* __restrict__ out,
                                 int R, int C) {
  __shared__ unsigned short tile[32][33];
  int c0 = blockIdx.x * 32, r0 = blockIdx.y * 32;
  int tx = threadIdx.x, ty = threadIdx.y; // 32 x 8
  for (int i = ty; i < 32; i += 8) {
    int row = r0 + i;
    int p = row & 63;
    int tr = (row & ~63) | ((p >> 2) | ((p & 3) << 4)); // true(row)
    tile[i][tx] = f2bf(in[(size_t)tr * C + c0 + tx]);
  }
  __syncthreads();
  for (int i = ty; i < 32; i += 8)
    out[(size_t)(c0 + i) * R + r0 + tx] = tile[tx][i];
}

// ---------------- finalize: un-permute via one __shfl per 64-block ----------------
// blocks [0,4096): aligned = sum(P[0..3])/rs ; [4096,12288): Kf = bf2f(Eb)/rs
__global__ void k_finalize(const float* __restrict__ P, float* __restrict__ aligned,
                           const unsigned short* __restrict__ Eb, float* __restrict__ Kf,
                           const float* __restrict__ rs) {
  const int b = blockIdx.x;
  const int lane = threadIdx.x & 63, w = threadIdx.x >> 6;
  const int src = ((lane & 15) << 2) | (lane >> 4); // stored pos holding true col `lane`
  if (b < 4096) {
    const size_t stride = (size_t)NSRC * DIM;
#pragma unroll
    for (int it = 0; it < 4; ++it) {
      int idx = b * 16 + w * 4 + it;   // 64-block index; 16 per row of DIM
      size_t base = (size_t)idx * 64;
      float r = 1.0f / rs[idx >> 4];
      float v = (P[base + lane] + P[base + stride + lane] +
                 P[base + 2 * stride + lane] + P[base + 3 * stride + lane]) * r;
      aligned[base + lane] = __shfl(v, src, 64);
    }
  } else {
    const int bb = b - 4096;
#pragma unroll
    for (int it = 0; it < 8; ++it) {
      int idx = bb * 32 + w * 8 + it;  // 64-block index; 64 per row of NTGT
      size_t base = (size_t)idx * 64;
      float r = 1.0f / rs[idx >> 6];
      float v = bf2f(Eb[base + lane]) * r;
      Kf[base + lane] = __shfl(v, src, 64);
    }
  }
}

// ---------------- m97-style NT bf16 GEMM, 128x128 tile, BK=32, 256 threads ----------------
// All epilogues store in the PERMUTED column layout (thread-contiguous vec4).
// EPI 0: dual proj (z selects set), +bias, bf16 out; row-sumsq atomics
// EPI 1: score: E=exp(-sqrt(max(sqs+sqt-2c,0))/T) bf16 out; row-sum atomics
// EPI 3: split-K (z = k-chunk), fp32 partial float4 stores
template <int EPI>
__global__ void __launch_bounds__(256)
k_gemm(const unsigned short* __restrict__ A0, const unsigned short* __restrict__ B0,
       const unsigned short* __restrict__ A1, const unsigned short* __restrict__ B1,
       int N, int K,
       const float* __restrict__ bias0, const float* __restrict__ bias1,
       unsigned short* __restrict__ Cb0, unsigned short* __restrict__ Cb1,
       float* __restrict__ Cf,
       const float* __restrict__ sqs, const float* __restrict__ sqt,
       const float* __restrict__ tempPtr,
       float* __restrict__ red0, float* __restrict__ red1,
       int KS) {
  __shared__ unsigned short ldsA[128 * 32];
  __shared__ unsigned short ldsB[128 * 32];
  __shared__ float rsum[128];

  const unsigned short* A = A0;
  const unsigned short* B = B0;
  const float* bias = bias0;
  unsigned short* Cb = Cb0;
  float* red = red0;
  int k0 = 0, k1 = K;
  if constexpr (EPI == 0) {
    if (blockIdx.z) { A = A1; B = B1; bias = bias1; Cb = Cb1; red = red1; }
  }
  if constexpr (EPI == 3) { k0 = blockIdx.z * KS; k1 = k0 + KS; }

  const int m0 = blockIdx.y * 128;
  const int n0 = blockIdx.x * 128;
  const int tid  = threadIdx.x;
  const int lane = tid & 63;
  const int wv   = tid >> 6;
  const int wm   = wv >> 1, wn = wv & 1;

  const int c0    = wv * 2;
  const int srow  = lane >> 2;
  const int skoff = (lane & 3) * 8;
  const unsigned short* ag[2]; const unsigned short* bg[2];
  unsigned short* la[2]; unsigned short* lb[2];
#pragma unroll
  for (int j = 0; j < 2; ++j) {
    int c = c0 + j;
    ag[j] = A + (size_t)(m0 + c * 16 + srow) * K + skoff;
    bg[j] = B + (size_t)(n0 + c * 16 + srow) * K + skoff;
    la[j] = ldsA + c * 512;
    lb[j] = ldsB + c * 512;
  }

  const fx4 fzero = {0.f, 0.f, 0.f, 0.f};
  fx4 acc[4][4];
#pragma unroll
  for (int i = 0; i < 4; ++i)
#pragma unroll
    for (int j = 0; j < 4; ++j) acc[i][j] = fzero;

  const int frow = lane & 15;
  const int kq   = lane >> 4;
  const int aoff = (wm * 64 + frow) * 32 + kq * 8;
  const int boff = (wn * 64 + frow) * 32 + kq * 8;

  for (int ko = k0; ko < k1; ko += 32) {
    gl_lds16(ag[0] + ko, la[0]);
    gl_lds16(ag[1] + ko, la[1]);
    gl_lds16(bg[0] + ko, lb[0]);
    gl_lds16(bg[1] + ko, lb[1]);
    __syncthreads();
    bf16x8 af[4], bfr[4];
#pragma unroll
    for (int t = 0; t < 4; ++t) af[t]  = *(const bf16x8*)(ldsA + aoff + t * 512);
#pragma unroll
    for (int t = 0; t < 4; ++t) bfr[t] = *(const bf16x8*)(ldsB + boff + t * 512);
#pragma unroll
    for (int i = 0; i < 4; ++i)
#pragma unroll
      for (int j = 0; j < 4; ++j)
        acc[i][j] = __builtin_amdgcn_mfma_f32_16x16x32_bf16(af[i], bfr[j], acc[i][j], 0, 0, 0);
    __syncthreads();
  }

  // C/D layout: true col = lane&15 + j*16, row = kq*4 + r (+i*16).
  // Store at permuted col s = frow*4 + j  ->  contiguous vec4 per thread.
  const int gcol0 = n0 + wn * 64 + frow;      // true col (for bias/sqt), + j*16
  const int scol  = n0 + wn * 64 + frow * 4;  // stored col base

  if constexpr (EPI == 0 || EPI == 1) {
    if (tid < 128) rsum[tid] = 0.f;
    __syncthreads();
    float invT = 0.f;
    if constexpr (EPI == 1) invT = 1.0f / tempPtr[0];
#pragma unroll
    for (int i = 0; i < 4; ++i)
#pragma unroll
      for (int r = 0; r < 4; ++r) {
        const int lrow = wm * 64 + kq * 4 + i * 16 + r;
        const int gm   = m0 + lrow;
        float si = 0.f;
        if constexpr (EPI == 1) si = sqs[gm];
        float racc = 0.f;
        ushort4 o;
        unsigned short* op = (unsigned short*)&o;
#pragma unroll
        for (int j = 0; j < 4; ++j) {
          float e;
          if constexpr (EPI == 0) {
            e = acc[i][j][r] + bias[gcol0 + j * 16];
          } else {
            float d2 = si + sqt[gcol0 + j * 16] - 2.0f * acc[i][j][r];
            float c = sqrtf(fmaxf(d2, 0.0f));
            e = __expf(-c * invT);
          }
          unsigned short eb = f2bf(e);
          op[j] = eb;
          float ev = bf2f(eb);
          racc += (EPI == 0) ? ev * ev : ev; // EPI0: sumsq of ROUNDED value
        }
        *(ushort4*)(Cb + (size_t)gm * N + scol) = o;
        racc += __shfl_xor(racc, 1, 64);
        racc += __shfl_xor(racc, 2, 64);
        racc += __shfl_xor(racc, 4, 64);
        racc += __shfl_xor(racc, 8, 64);
        if (frow == 0) atomicAdd(&rsum[lrow], racc);
      }
    __syncthreads();
    if (tid < 128) atomicAdd(&red[m0 + tid], rsum[tid]);
  } else { // EPI == 3: fp32 partials, permuted float4 stores
    float* Pz = Cf + (size_t)blockIdx.z * NSRC * DIM;
#pragma unroll
    for (int i = 0; i < 4; ++i)
#pragma unroll
      for (int r = 0; r < 4; ++r) {
        const int gm = m0 + wm * 64 + kq * 4 + i * 16 + r;
        float4 v = make_float4(acc[i][0][r], acc[i][1][r], acc[i][2][r], acc[i][3][r]);
        *(float4*)(Pz + (size_t)gm * N + scol) = v;
      }
  }
}

// ---------------- launch ----------------
extern "C" void kernel_launch(void* const* d_in, const int* in_sizes, int n_in,
                              void* d_out, int out_size, void* d_ws, size_t ws_size,
                              hipStream_t stream) {
  const float* source = (const float*)d_in[0];
  const float* target = (const float*)d_in[1];
  const float* W_src  = (const float*)d_in[2];
  const float* b_src  = (const float*)d_in[3];
  const float* W_tgt  = (const float*)d_in[4];
  const float* b_tgt  = (const float*)d_in[5];
  const float* temp   = (const float*)d_in[6];

  float* out     = (float*)d_out;
  float* aligned = out;                         // [NSRC][DIM]
  float* Kout    = out + (size_t)NSRC * DIM;    // final K; staging for split-K partials
  float* parts   = Kout;                        // 4 x [NSRC][DIM] fp32 = exactly 64 MB

  char* ws = (char*)d_ws;
  unsigned short* src_b  = (unsigned short*)(ws + 0);
  unsigned short* tgt_b  = (unsigned short*)(ws + 8388608);
  unsigned short* Wsrc_b = (unsigned short*)(ws + 16777216);
  unsigned short* Wtgt_b = (unsigned short*)(ws + 18874368);
  unsigned short* sp_b   = (unsigned short*)(ws + 20971520);
  unsigned short* tp_b   = (unsigned short*)(ws + 29360128);
  unsigned short* tgtT_b = (unsigned short*)(ws + 37748736);
  unsigned short* E_b    = (unsigned short*)(ws + 46137344); // 32 MB
  float* sq_s  = (float*)(ws + 79691776);                    // 16 KB
  float* sq_t  = (float*)(ws + 79708160);                    // 16 KB
  float* rsums = (float*)(ws + 79724544);                    // 16 KB

  // 0) zero sq_s, sq_t, rsums (contiguous 48 KB)
  hipMemsetAsync(sq_s, 0, 3 * NSRC * sizeof(float), stream);

  // 1) conversions + permuted target transpose
  k_convert_all<<<10240, 256, 0, stream>>>(source, target, W_src, W_tgt,
                                           src_b, tgt_b, Wsrc_b, Wtgt_b);
  k_transpose_bf16<<<dim3(DIM / 32, NTGT / 32), dim3(32, 8), 0, stream>>>(target, tgtT_b, NTGT, DIM);

  // 2) both projections (z selects problem); outputs permuted in DIM; row-sumsq fused
  k_gemm<0><<<dim3(DIM / 128, NSRC / 128, 2), 256, 0, stream>>>(
      src_b, Wsrc_b, tgt_b, Wtgt_b, DIM, DIM, b_src, b_tgt, sp_b, tp_b,
      nullptr, nullptr, nullptr, nullptr, sq_s, sq_t, 0);

  // 3) score: E bf16 (permuted in NTGT) -> ws, row sums -> rsums
  k_gemm<1><<<dim3(NTGT / 128, NSRC / 128, 1), 256, 0, stream>>>(
      sp_b, tp_b, nullptr, nullptr, NTGT, DIM, nullptr, nullptr, E_b, nullptr,
      nullptr, sq_s, sq_t, temp, rsums, nullptr, 0);

  // 4) E @ target: split-K x4, permuted float4 partial stores into d_out K region
  k_gemm<3><<<dim3(DIM / 128, NSRC / 128, 4), 256, 0, stream>>>(
      E_b, tgtT_b, nullptr, nullptr, DIM, NTGT, nullptr, nullptr, nullptr, nullptr,
      parts, nullptr, nullptr, nullptr, nullptr, nullptr, NTGT / 4);

  // 5) finalize: merge partials /rs -> aligned ; K = bf2f(E_b)/rs (both un-permuted)
  k_finalize<<<12288, 256, 0, stream>>>(parts, aligned, E_b, Kout, rsums);
}